// Round 10
// baseline (150.197 us; speedup 1.0000x reference)
//
#include <hip/hip_runtime.h>
#include <stdint.h>

// DILATE loss, B=32, L=512, DIM=16, gamma=1e-3, alpha=0.5.
//
// Round-10 structure:
//   kA : D[b][j][i] column-major with PRE=352/POST=8 pad columns.
//   kP : ONE 256-thread block (4 waves) per batch. Global skewed hard-min
//        wavefront carrying R (DTW value) and T (= sum (i-j)^2 along the
//        argmin path). Lane L owns rows {2L, 2L+1}; processes column
//        c = t - L - 32*w at step t (DLAG=32 per wave). Within-wave
//        boundary via DPP wave_shr:1; cross-wave via 64-slot LDS ring,
//        barrier every 16 steps (lag analysis: writes precede reads by
//        >=17 steps -> always barrier-separated; drift bounded by barrier).
//        Junk cells (c outside [0,512)) are self-contained: pad D values
//        clamped >=0 so junk R >= 1e10 and is never argmin for real cells.
//   kC : combine -> scalar loss.
// Tie priority (unchanged, verified absmax 0.0): diag > up > left.

#define N 512
#define NB 32
#define BIGF 1e10f
#define PRE 352
#define POST 8
#define NCOL (PRE + N + POST)          // 872
#define STRF ((size_t)NCOL * N)        // floats per batch
#define DLAG 32
#define NBLK 54                        // 54 * 16 = 864 steps, covers t=862

typedef unsigned int u32;
typedef float f32x4 __attribute__((ext_vector_type(4)));

__device__ __forceinline__ float dppshr(float x, float oldv) {
    // lane l gets lane l-1's x; lane 0 gets oldv (bound_ctrl=false keeps old)
    return __int_as_float(__builtin_amdgcn_update_dpp(
        __float_as_int(oldv), __float_as_int(x), 0x138, 0xF, 0xF, false));
}

// ---------------- kA: pairwise squared distances, column-major -------------
__global__ __launch_bounds__(512) void kA(const float* __restrict__ inp,
                                          const float* __restrict__ tgt,
                                          float* __restrict__ Dg) {
    const int b = blockIdx.y;
    const int jc = blockIdx.x;         // group of 4 columns
    const int tid = (int)threadIdx.x;  // row index i in [0,512)
    __shared__ float xs[4][16];        // x[j] = inp[b,j]-inp[b,0]
    if (tid < 64) {
        int c = tid >> 4, d = tid & 15;
        int j = jc * 4 + c;
        xs[c][d] = inp[(((size_t)b * N + j) << 4) + d] -
                   inp[(((size_t)b * N) << 4) + d];
    }
    __syncthreads();
    const float4* t4 = (const float4*)(tgt + (((size_t)b * N + tid) << 4));
    float4 ta = t4[0], tb = t4[1], tc = t4[2], td = t4[3];
    float* out = Dg + (size_t)b * STRF + ((size_t)(PRE + jc * 4)) * N + tid;
#pragma unroll
    for (int c = 0; c < 4; ++c) {
        float s = 0.f, e;
        e = ta.x - xs[c][0];  s = fmaf(e, e, s);
        e = ta.y - xs[c][1];  s = fmaf(e, e, s);
        e = ta.z - xs[c][2];  s = fmaf(e, e, s);
        e = ta.w - xs[c][3];  s = fmaf(e, e, s);
        e = tb.x - xs[c][4];  s = fmaf(e, e, s);
        e = tb.y - xs[c][5];  s = fmaf(e, e, s);
        e = tb.z - xs[c][6];  s = fmaf(e, e, s);
        e = tb.w - xs[c][7];  s = fmaf(e, e, s);
        e = tc.x - xs[c][8];  s = fmaf(e, e, s);
        e = tc.y - xs[c][9];  s = fmaf(e, e, s);
        e = tc.z - xs[c][10]; s = fmaf(e, e, s);
        e = tc.w - xs[c][11]; s = fmaf(e, e, s);
        e = td.x - xs[c][12]; s = fmaf(e, e, s);
        e = td.y - xs[c][13]; s = fmaf(e, e, s);
        e = td.z - xs[c][14]; s = fmaf(e, e, s);
        e = td.w - xs[c][15]; s = fmaf(e, e, s);
        out[(size_t)c * N] = s;
    }
}

// ---------------- kP: 4-wave pipelined wavefront DP ------------------------
__global__ __launch_bounds__(256) void kP(const float* __restrict__ Dg,
                                          float* __restrict__ acc) {
    const int b = blockIdx.x;
    const int tid = (int)threadIdx.x;
    const int w = tid >> 6, lam = tid & 63;
    const int off = tid + w * DLAG;  // lane's step offset (= L + 32w)
    const char* DbB = (const char*)(Dg + (size_t)b * STRF);

    __shared__ __align__(16) float2 ring[3][64];
    __shared__ float2 dump[256];

    // init ring/dump to (BIGF, 0): junk-region up-values must be huge
    if (tid < 192) ((float2*)ring)[tid] = make_float2(BIGF, 0.f);
    dump[tid] = make_float2(BIGF, 0.f);
    __syncthreads();

    const bool is_prod = (lam == 63) && (w < 3);
    const bool is_cons = (lam == 0) && (w > 0);
    float2* ringW = is_prod ? &ring[w][0] : &dump[tid];
    const float2* ringR = (w > 0) ? &ring[w - 1][0] : &ring[0][0];

    // D addressing: byte voffset = (PRE + t - off)*2048 + tid*8, clamped to
    // column <= 511 (junk steps re-read col 511: harmless, cells are junk)
    const int vLane = tid * 8 - off * 2048;
    const int vMax = (PRE + 511) * 2048 + tid * 8;

    float2 dbA[8], dbB[8];
    f32x4 fA0, fA1, fA2, fA3, fB0, fB1, fB2, fB3;

#define ISSUE(BANK, TB)                                                       \
    do {                                                                      \
        _Pragma("unroll") for (int k_ = 0; k_ < 8; ++k_) {                    \
            int vo = min((PRE + (TB) + k_) * 2048 + vLane, vMax);             \
            BANK[k_] = *(const float2*)(DbB + vo);                            \
        }                                                                     \
    } while (0)

    // state
    float Rp0 = BIGF, Rp1 = BIGF, Tp0 = 0.f, Tp1 = 0.f;
    float upR = BIGF, upT = 0.f;
    float dgR = (tid == 0) ? 0.f : BIGF, dgT = 0.f;
    float dr0 = (float)(2 * tid + off), dr1 = dr0 + 1.0f;
    int ci = -off;
    float Rfin = 0.f, Tfin = 0.f;
    int rb = (-96 * w) & 63;

    // prime fifo bank A (covers steps [0,8)) and D banks (steps [0,16))
    if (is_cons) {
        const f32x4* q = (const f32x4*)(ringR + rb);
        fA0 = q[0]; fA1 = q[1]; fA2 = q[2]; fA3 = q[3];
    }
    rb = (rb + 8) & 63;
    ISSUE(dbA, 0);
    ISSUE(dbB, 8);

#define STEP(DD, FR, FT)                                                      \
    do {                                                                      \
        float D0 = fmaxf((DD).x, 0.f), D1 = fmaxf((DD).y, 0.f);               \
        float mn0 = fminf(upR, fminf(dgR, Rp0));                              \
        float Ts0 = (mn0 == dgR) ? dgT : ((mn0 == upR) ? upT : Tp0);          \
        float R0 = D0 + mn0;                                                  \
        float T0 = fmaf(dr0, dr0, Ts0);                                       \
        float mn1 = fminf(R0, fminf(Rp0, Rp1));                               \
        float Ts1 = (mn1 == Rp0) ? Tp0 : ((mn1 == R0) ? T0 : Tp1);            \
        float R1 = D1 + mn1;                                                  \
        float T1 = fmaf(dr1, dr1, Ts1);                                       \
        bool hit = (ci == 511);                                               \
        Rfin = hit ? R1 : Rfin;                                               \
        Tfin = hit ? T1 : Tfin;                                               \
        if (is_prod && (u32)ci < 512u)                                        \
            ringW[ci & 63] = make_float2(R1, T1);                             \
        Rp0 = R0; Tp0 = T0; Rp1 = R1; Tp1 = T1;                               \
        dgR = upR; dgT = upT;                                                 \
        float bR = dppshr(R1, BIGF), bT = dppshr(T1, 0.f);                    \
        upR = is_cons ? (FR) : bR;                                            \
        upT = is_cons ? (FT) : bT;                                            \
        dr0 -= 1.f; dr1 -= 1.f; ci += 1;                                      \
    } while (0)

    for (int n = 0; n < NBLK; ++n) {
        asm volatile("s_waitcnt lgkmcnt(0)" ::: "memory");
        __builtin_amdgcn_s_barrier();
        // fifo bank B: covers steps [16n+8, 16n+16)
        if (is_cons) {
            const f32x4* q = (const f32x4*)(ringR + rb);
            fB0 = q[0]; fB1 = q[1]; fB2 = q[2]; fB3 = q[3];
        }
        rb = (rb + 8) & 63;
        STEP(dbA[0], fA0[2], fA0[3]);
        STEP(dbA[1], fA1[0], fA1[1]);
        STEP(dbA[2], fA1[2], fA1[3]);
        STEP(dbA[3], fA2[0], fA2[1]);
        STEP(dbA[4], fA2[2], fA2[3]);
        STEP(dbA[5], fA3[0], fA3[1]);
        STEP(dbA[6], fA3[2], fA3[3]);
        STEP(dbA[7], fB0[0], fB0[1]);
        // fifo bank A: covers steps [16n+16, 16n+24)
        if (is_cons) {
            const f32x4* q = (const f32x4*)(ringR + rb);
            fA0 = q[0]; fA1 = q[1]; fA2 = q[2]; fA3 = q[3];
        }
        rb = (rb + 8) & 63;
        ISSUE(dbA, 16 * n + 16);  // D for next block's first half
        STEP(dbB[0], fB0[2], fB0[3]);
        STEP(dbB[1], fB1[0], fB1[1]);
        STEP(dbB[2], fB1[2], fB1[3]);
        STEP(dbB[3], fB2[0], fB2[1]);
        STEP(dbB[4], fB2[2], fB2[3]);
        STEP(dbB[5], fB3[0], fB3[1]);
        STEP(dbB[6], fB3[2], fB3[3]);
        STEP(dbB[7], fA0[0], fA0[1]);
        ISSUE(dbB, 16 * n + 24);  // D for next block's second half
    }
#undef STEP
#undef ISSUE

    if (tid == 255) {
        acc[b] = Rfin;       // Rp[N,N]: hard-DTW value
        acc[NB + b] = Tfin;  // sum (i-j)^2 along argmin path
    }
}

// ---------------- kC: combine over batches ---------------------------------
__global__ void kC(const float* __restrict__ acc, float* __restrict__ out) {
    const int l = (int)threadIdx.x;
    float vs = (l < NB) ? acc[l] : 0.f;
    float vt = (l < NB) ? acc[NB + l] : 0.f;
#pragma unroll
    for (int o = 32; o >= 1; o >>= 1) {
        vs += __shfl_down(vs, o);
        vt += __shfl_down(vt, o);
    }
    if (l == 0)
        out[0] = 0.5f * (vs / (float)NB) +
                 0.5f * (vt / ((float)NB * (float)(N * N)));
}

__global__ void kSentinel(float* out) { out[0] = -12345.0f; }

extern "C" void kernel_launch(void* const* d_in, const int* in_sizes, int n_in,
                              void* d_out, int out_size, void* d_ws, size_t ws_size,
                              hipStream_t stream) {
    const float* inp = (const float*)d_in[0];
    const float* tgt = (const float*)d_in[1];
    float* out = (float*)d_out;

    const size_t DSZ = (size_t)NB * STRF * sizeof(float);  // ~57 MiB padded
    const size_t NEEDED = 256 + DSZ;
    if (ws_size < NEEDED) {
        kSentinel<<<1, 1, 0, stream>>>(out);
        return;
    }
    char* ws = (char*)d_ws;
    float* acc = (float*)ws;  // [0..31] shape, [32..63] temporal
    float* Dg = (float*)(ws + 256);

    kA<<<dim3(N / 4, NB), 512, 0, stream>>>(inp, tgt, Dg);
    kP<<<NB, 256, 0, stream>>>(Dg, acc);
    kC<<<1, 64, 0, stream>>>(acc, out);
}

// Round 11
// 106.547 us; speedup vs baseline: 1.4097x; 1.4097x over previous
//
#include <hip/hip_runtime.h>
#include <stdint.h>

// DILATE loss, B=32, L=512, DIM=16, gamma=1e-3, alpha=0.5.
//
// Round-11 structure:
//   kA : D[b][col][row] column-major with PRE=128/POST=144 ZERO pad columns
//        (pad removes all clamping/masking/phases from the DP kernel).
//   kFT: one wave per batch, skew-2 forward hard-min DP carrying R (DTW
//        value) and T (= sum (i-j)^2 along the argmin path).
//        Lane l owns rows 8l+1..8l+8; macro-step T processes cols
//        cA=2(T-l), cB=cA+1 (0-based), T=0..319.
//        D loads: 4-slot INLINE-ASM pipeline (4x global_load_dwordx4 per
//        slot, imm offsets 0/16/2048/2064) with counted s_waitcnt vmcnt(12)
//        carrying "+v" register deps -- the compiler can neither sink the
//        loads (asm volatile) nor hoist consumers above the wait (data dep).
//        R8/R9/R10 all showed hipcc sinking C-level prefetch (VGPR=56..60).
//        Boundary handoff via DPP wave_shr (lane0 gets BIGF/0 fallback).
//        Junk cells (pad cols) self-contained: R_junk = 0 + BIGF = BIGF
//        exactly; never argmin for real cells (validated in R10).
//   kC : combine -> scalar loss.
// Tie priority (unchanged, verified absmax 0.0): diag > up > left.

#define N 512
#define NB 32
#define BIGF 1e10f
#define PRE 128
#define POST 144
#define NCOL (PRE + N + POST)    // 784 columns
#define STRF ((size_t)NCOL * N)  // floats per batch

typedef unsigned int u32;
typedef float f32x4 __attribute__((ext_vector_type(4)));

__device__ __forceinline__ float dppshr(float x, float oldv) {
    // lane l gets lane l-1's x; lane 0 keeps oldv (bound_ctrl=false)
    return __int_as_float(__builtin_amdgcn_update_dpp(
        __float_as_int(oldv), __float_as_int(x), 0x138, 0xF, 0xF, false));
}

// ---------------- kA: pairwise squared distances + zero pads ---------------
__global__ __launch_bounds__(512) void kA(const float* __restrict__ inp,
                                          const float* __restrict__ tgt,
                                          float* __restrict__ Dg) {
    const int b = blockIdx.y;
    const int col0 = blockIdx.x * 4;   // global column group
    const int tid = (int)threadIdx.x;  // row index i in [0,512)
    float* out = Dg + (size_t)b * STRF + (size_t)col0 * N + tid;
    if (col0 < PRE || col0 >= PRE + N) {  // pad block: zeros
#pragma unroll
        for (int c = 0; c < 4; ++c) out[(size_t)c * N] = 0.f;
        return;
    }
    const int jc = (col0 - PRE) >> 2;  // real column group in [0,128)
    __shared__ float xs[4][16];        // x[j] = inp[b,j]-inp[b,0]
    if (tid < 64) {
        int c = tid >> 4, d = tid & 15;
        int j = jc * 4 + c;
        xs[c][d] = inp[(((size_t)b * N + j) << 4) + d] -
                   inp[(((size_t)b * N) << 4) + d];
    }
    __syncthreads();
    const float4* t4 = (const float4*)(tgt + (((size_t)b * N + tid) << 4));
    float4 ta = t4[0], tb = t4[1], tc = t4[2], td = t4[3];
#pragma unroll
    for (int c = 0; c < 4; ++c) {
        float s = 0.f, e;
        e = ta.x - xs[c][0];  s = fmaf(e, e, s);
        e = ta.y - xs[c][1];  s = fmaf(e, e, s);
        e = ta.z - xs[c][2];  s = fmaf(e, e, s);
        e = ta.w - xs[c][3];  s = fmaf(e, e, s);
        e = tb.x - xs[c][4];  s = fmaf(e, e, s);
        e = tb.y - xs[c][5];  s = fmaf(e, e, s);
        e = tb.z - xs[c][6];  s = fmaf(e, e, s);
        e = tb.w - xs[c][7];  s = fmaf(e, e, s);
        e = tc.x - xs[c][8];  s = fmaf(e, e, s);
        e = tc.y - xs[c][9];  s = fmaf(e, e, s);
        e = tc.z - xs[c][10]; s = fmaf(e, e, s);
        e = tc.w - xs[c][11]; s = fmaf(e, e, s);
        e = td.x - xs[c][12]; s = fmaf(e, e, s);
        e = td.y - xs[c][13]; s = fmaf(e, e, s);
        e = td.z - xs[c][14]; s = fmaf(e, e, s);
        e = td.w - xs[c][15]; s = fmaf(e, e, s);
        out[(size_t)c * N] = s;
    }
}

// ---------------- kFT: skew-2 DP, asm-pipelined loads ----------------------
__global__ __launch_bounds__(64) void kFT(const float* __restrict__ Dg,
                                          float* __restrict__ acc) {
    const int b = blockIdx.x;
    const int l = (int)threadIdx.x;
    const float* __restrict__ Db = Dg + (size_t)b * STRF;

    // slot registers: colA rows0-3/4-7, colB rows0-3/4-7
    f32x4 A0s0, A1s0, B0s0, B1s0, A0s1, A1s1, B0s1, B1s1;
    f32x4 A0s2, A1s2, B0s2, B1s2, A0s3, A1s3, B0s3, B1s3;
    u32 vo0, vo1, vo2, vo3;

    // slot s (covering macro-step T=s+4k): byte off (PRE + 2(T-l))*2048 + l*32
    const u32 vbase = (u32)((PRE - 2 * l) * 2048 + l * 32);
    vo0 = vbase; vo1 = vbase + 4096; vo2 = vbase + 8192; vo3 = vbase + 12288;

#define LOADS(s_)                                                             \
    asm volatile(                                                             \
        "global_load_dwordx4 %0, %4, %5\n\t"                                  \
        "global_load_dwordx4 %1, %4, %5 offset:16\n\t"                        \
        "global_load_dwordx4 %2, %4, %5 offset:2048\n\t"                      \
        "global_load_dwordx4 %3, %4, %5 offset:2064"                          \
        : "=v"(A0s##s_), "=v"(A1s##s_), "=v"(B0s##s_), "=v"(B1s##s_)          \
        : "v"(vo##s_), "s"(Db))

#define WAITS(s_)                                                             \
    asm volatile("s_waitcnt vmcnt(12)"                                        \
                 : "+v"(A0s##s_), "+v"(A1s##s_), "+v"(B0s##s_), "+v"(B1s##s_))

    LOADS(0); LOADS(1); LOADS(2); LOADS(3);

    float Rp[8], Tp[8], Xc[8], Xt[8];
#pragma unroll
    for (int r = 0; r < 8; ++r) { Rp[r] = BIGF; Tp[r] = 0.f; }
    float sA = BIGF, sB = BIGF, tA = 0.f, tB = 0.f;
    float sBold = (l == 0) ? 0.f : BIGF, tBold = 0.f;  // (1,1): dg=Rp[0][0]=0
    float db = (float)(10 * l);  // (i-j) at colA r=0; -2 per step
    float Rfin = 0.f, Tfin = 0.f;
    int cp = -l;  // cpair = T - l

    // one column of 8 rows; serial chain cr[r-1] -> cr[r]
#define CELLS(upB, dgB, utB, dtB, DL, DH, pr, pt, cr, ct, dbq)                \
    _Pragma("unroll") for (int r = 0; r < 8; ++r) {                           \
        float up = (r == 0) ? (upB) : cr[r - 1];                              \
        float dg = (r == 0) ? (dgB) : pr[r - 1];                              \
        float lf = pr[r];                                                     \
        float ut = (r == 0) ? (utB) : ct[r - 1];                              \
        float dt = (r == 0) ? (dtB) : pt[r - 1];                              \
        float lt = pt[r];                                                     \
        float mn = fminf(up, fminf(dg, lf));                                  \
        float Ts = (mn == dg) ? dt : ((mn == up) ? ut : lt);                  \
        float dr = (dbq) + (float)r;                                          \
        ct[r] = fmaf(dr, dr, Ts);                                             \
        cr[r] = ((r < 4) ? (DL)[r & 3] : (DH)[r & 3]) + mn;                   \
    }

#define MSTEP(s_)                                                             \
    do {                                                                      \
        WAITS(s_);                                                            \
        CELLS(sA, sBold, tA, tBold, A0s##s_, A1s##s_, Rp, Tp, Xc, Xt, db);    \
        CELLS(sB, sA, tB, tA, B0s##s_, B1s##s_, Xc, Xt, Rp, Tp, db - 1.f);    \
        if (cp == 255) { Rfin = Rp[7]; Tfin = Tp[7]; }                        \
        sBold = sB; tBold = tB;                                               \
        sA = dppshr(Xc[7], BIGF); tA = dppshr(Xt[7], 0.f);                    \
        sB = dppshr(Rp[7], BIGF); tB = dppshr(Tp[7], 0.f);                    \
        db -= 2.0f; cp += 1;                                                  \
        vo##s_ += 16384; /* +8 columns for next use of this slot */           \
        LOADS(s_);                                                            \
    } while (0)

    for (int g = 0; g < 80; ++g) {  // T = 4g + s, total 320 macro-steps
        MSTEP(0); MSTEP(1); MSTEP(2); MSTEP(3);
    }
#undef MSTEP
#undef CELLS
#undef WAITS
#undef LOADS

    asm volatile("s_waitcnt vmcnt(0)" ::: "memory");  // drain before exit
    if (l == 63) {
        acc[b] = Rfin;       // Rp[N,N]: hard-DTW value
        acc[NB + b] = Tfin;  // sum (i-j)^2 along argmin path
    }
}

// ---------------- kC: combine over batches ---------------------------------
__global__ void kC(const float* __restrict__ acc, float* __restrict__ out) {
    const int l = (int)threadIdx.x;
    float vs = (l < NB) ? acc[l] : 0.f;
    float vt = (l < NB) ? acc[NB + l] : 0.f;
#pragma unroll
    for (int o = 32; o >= 1; o >>= 1) {
        vs += __shfl_down(vs, o);
        vt += __shfl_down(vt, o);
    }
    if (l == 0)
        out[0] = 0.5f * (vs / (float)NB) +
                 0.5f * (vt / ((float)NB * (float)(N * N)));
}

__global__ void kSentinel(float* out) { out[0] = -12345.0f; }

extern "C" void kernel_launch(void* const* d_in, const int* in_sizes, int n_in,
                              void* d_out, int out_size, void* d_ws, size_t ws_size,
                              hipStream_t stream) {
    const float* inp = (const float*)d_in[0];
    const float* tgt = (const float*)d_in[1];
    float* out = (float*)d_out;

    const size_t DSZ = (size_t)NB * STRF * sizeof(float);  // ~51.4 MiB
    const size_t NEEDED = 256 + DSZ;
    if (ws_size < NEEDED) {
        kSentinel<<<1, 1, 0, stream>>>(out);
        return;
    }
    char* ws = (char*)d_ws;
    float* acc = (float*)ws;  // [0..31] shape, [32..63] temporal
    float* Dg = (float*)(ws + 256);

    kA<<<dim3(NCOL / 4, NB), 512, 0, stream>>>(inp, tgt, Dg);
    kFT<<<NB, 64, 0, stream>>>(Dg, acc);
    kC<<<1, 64, 0, stream>>>(acc, out);
}